// Round 9
// baseline (45.546 us; speedup 1.0000x reference)
//
#include <hip/hip_runtime.h>

#define NBINS 10
#define C 10

constexpr int BLOCK = 256;
constexpr int GRID  = 2048;
constexpr int PSTR  = 32;     // padded partial-row stride (floats)

// d_ws float layout: 3 segments of GRID*PSTR floats (conf | cnt | cor).
// Every slot read by ece_reduce is rewritten every call — no memset needed.

__global__ __launch_bounds__(BLOCK) void ece_pass(
    const float4* __restrict__ p4,
    const int2*   __restrict__ l2,
    float*        __restrict__ part,
    int npairs)
{
    __shared__ float        s_red[8 * NBINS];
    __shared__ unsigned int s_cor[NBINS];

    const int tid  = threadIdx.x;
    const int lane = tid & 63, wave = tid >> 6;

    const float EDGE[NBINS] = {
        (float)(0*0.1), (float)(1*0.1), (float)(2*0.1), (float)(3*0.1), (float)(4*0.1),
        (float)(5*0.1), (float)(6*0.1), (float)(7*0.1), (float)(8*0.1), (float)(9*0.1)};

    if (tid < NBINS) s_cor[tid] = 0u;
    __syncthreads();

    float        conf[NBINS];
    unsigned int cnt1[NBINS];           // edges 1..9 ([0] unused)
    unsigned int np = 0;                // pairs processed -> cnt[0] = 20*np (x>0 always)
#pragma unroll
    for (int t = 0; t < NBINS; ++t) { conf[t] = 0.0f; cnt1[t] = 0u; }

    // ladder for one element: shares one v_cmp between count (addc) and conf (cndmask+add)
#define LADDER(x)                                                           \
        {                                                                   \
            _Pragma("unroll")                                               \
            for (int t_ = 1; t_ < NBINS; ++t_) {                            \
                const bool g_ = (x) > EDGE[t_];                             \
                cnt1[t_] += g_ ? 1u : 0u;                                   \
                conf[t_] += g_ ? (x) : 0.0f;                                \
            }                                                               \
        }

    for (int pr = blockIdx.x * BLOCK + tid; pr < npairs; pr += GRID * BLOCK) {
        const float4* rw = p4 + (size_t)pr * 5;    // 80 B contiguous per lane
        const float4 q0 = rw[0], q1 = rw[1], q2 = rw[2], q3 = rw[3], q4 = rw[4];
        const int2 lab = l2[pr];
        ++np;

        // ---- cumulative histogram over all 20 elements ----
        conf[0] += (((q0.x + q0.y) + (q0.z + q0.w)) + ((q1.x + q1.y) + (q1.z + q1.w)))
                 + (((q2.x + q2.y) + (q2.z + q2.w)) + ((q3.x + q3.y) + (q3.z + q3.w)))
                 + ((q4.x + q4.y) + (q4.z + q4.w));
        LADDER(q0.x); LADDER(q0.y); LADDER(q0.z); LADDER(q0.w);
        LADDER(q1.x); LADDER(q1.y); LADDER(q1.z); LADDER(q1.w);
        LADDER(q2.x); LADDER(q2.y); LADDER(q2.z); LADDER(q2.w);
        LADDER(q3.x); LADDER(q3.y); LADDER(q3.z); LADDER(q3.w);
        LADDER(q4.x); LADDER(q4.y); LADDER(q4.z); LADDER(q4.w);

        // ---- sample A: elems 0..9 ----
        const float mA = fmaxf(fmaxf(fmaxf(fmaxf(q0.x, q0.y), fmaxf(q0.z, q0.w)),
                                     fmaxf(fmaxf(q1.x, q1.y), fmaxf(q1.z, q1.w))),
                               fmaxf(q2.x, q2.y));
        float plA = q0.x;                          // p[label] via cndmask chain
        plA = (lab.x == 1) ? q0.y : plA;
        plA = (lab.x == 2) ? q0.z : plA;
        plA = (lab.x == 3) ? q0.w : plA;
        plA = (lab.x == 4) ? q1.x : plA;
        plA = (lab.x == 5) ? q1.y : plA;
        plA = (lab.x == 6) ? q1.z : plA;
        plA = (lab.x == 7) ? q1.w : plA;
        plA = (lab.x == 8) ? q2.x : plA;
        plA = (lab.x == 9) ? q2.y : plA;
        if (plA >= mA) {                           // == max -> predicted correct
            const int im = min((int)ceilf(plA * 10.0f) - 1, NBINS - 1);
            if (im >= 0) atomicAdd(&s_cor[im], 1u);   // LDS only, ~10% hit rate
        }

        // ---- sample B: elems 10..19 ----
        const float mB = fmaxf(fmaxf(fmaxf(fmaxf(q2.z, q2.w), fmaxf(q3.x, q3.y)),
                                     fmaxf(fmaxf(q3.z, q3.w), fmaxf(q4.x, q4.y))),
                               fmaxf(q4.z, q4.w));
        float plB = q2.z;
        plB = (lab.y == 1) ? q2.w : plB;
        plB = (lab.y == 2) ? q3.x : plB;
        plB = (lab.y == 3) ? q3.y : plB;
        plB = (lab.y == 4) ? q3.z : plB;
        plB = (lab.y == 5) ? q3.w : plB;
        plB = (lab.y == 6) ? q4.x : plB;
        plB = (lab.y == 7) ? q4.y : plB;
        plB = (lab.y == 8) ? q4.z : plB;
        plB = (lab.y == 9) ? q4.w : plB;
        if (plB >= mB) {
            const int im = min((int)ceilf(plB * 10.0f) - 1, NBINS - 1);
            if (im >= 0) atomicAdd(&s_cor[im], 1u);
        }
    }
#undef LADDER

    unsigned int cnt0 = 20u * np;       // all elements > 0 (softmax output)

    // ---- 64-lane butterfly ----
#pragma unroll
    for (int t = 0; t < NBINS; ++t)
        for (int o = 32; o > 0; o >>= 1)
            conf[t] += __shfl_xor(conf[t], o, 64);
    for (int o = 32; o > 0; o >>= 1) cnt0 += __shfl_xor(cnt0, o, 64);
#pragma unroll
    for (int t = 1; t < NBINS; ++t)
        for (int o = 32; o > 0; o >>= 1)
            cnt1[t] += __shfl_xor(cnt1[t], o, 64);

    if (lane == 0) {
#pragma unroll
        for (int t = 0; t < NBINS; ++t) {
            s_red[wave * NBINS + t]       = conf[t];
            s_red[(4 + wave) * NBINS + t] = (t == 0) ? (float)cnt0 : (float)cnt1[t];
        }
    }
    __syncthreads();

    if (tid < 12) {   // 12 slots (2 zero pads) so reduce can float4-load
        float fc = 0.0f, fn = 0.0f;
        if (tid < NBINS) {
#pragma unroll
            for (int w = 0; w < 4; ++w) {
                fc += s_red[w * NBINS + tid];
                fn += s_red[(4 + w) * NBINS + tid];
            }
        }
        const float fr = (tid < NBINS) ? (float)s_cor[tid] : 0.0f;
        part[(size_t)blockIdx.x * PSTR + tid]                    = fc;
        part[(size_t)GRID * PSTR + blockIdx.x * PSTR + tid]      = fn;
        part[(size_t)2 * GRID * PSTR + blockIdx.x * PSTR + tid]  = fr;
    }
}

__global__ __launch_bounds__(256) void ece_reduce(
    const float* __restrict__ part,
    float* __restrict__ out)
{
    __shared__ double s_c[4][NBINS];
    __shared__ double s_n[4][NBINS];
    __shared__ double s_r[4][NBINS];

    const int tid = threadIdx.x;
    const int lane = tid & 63, wave = tid >> 6;

    double conf[NBINS], cntd[NBINS], cord[NBINS];
#pragma unroll
    for (int t = 0; t < NBINS; ++t) { conf[t] = 0.0; cntd[t] = 0.0; cord[t] = 0.0; }

    for (int b = tid; b < GRID; b += 256) {
        const float4* rc = reinterpret_cast<const float4*>(part + (size_t)b * PSTR);
        const float4* rn = reinterpret_cast<const float4*>(part + (size_t)GRID * PSTR + b * PSTR);
        const float4* rr = reinterpret_cast<const float4*>(part + (size_t)2 * GRID * PSTR + b * PSTR);
        const float4 c0 = rc[0], c1 = rc[1], c2 = rc[2];
        const float4 n0 = rn[0], n1 = rn[1], n2 = rn[2];
        const float4 r0 = rr[0], r1 = rr[1], r2 = rr[2];
        const float cf[12] = {c0.x,c0.y,c0.z,c0.w, c1.x,c1.y,c1.z,c1.w, c2.x,c2.y,c2.z,c2.w};
        const float nf[12] = {n0.x,n0.y,n0.z,n0.w, n1.x,n1.y,n1.z,n1.w, n2.x,n2.y,n2.z,n2.w};
        const float rf[12] = {r0.x,r0.y,r0.z,r0.w, r1.x,r1.y,r1.z,r1.w, r2.x,r2.y,r2.z,r2.w};
#pragma unroll
        for (int t = 0; t < NBINS; ++t) {
            conf[t] += (double)cf[t];
            cntd[t] += (double)nf[t];
            cord[t] += (double)rf[t];
        }
    }

#pragma unroll
    for (int t = 0; t < NBINS; ++t) {
        for (int o = 32; o > 0; o >>= 1) {
            conf[t] += __shfl_xor(conf[t], o, 64);
            cntd[t] += __shfl_xor(cntd[t], o, 64);
            cord[t] += __shfl_xor(cord[t], o, 64);
        }
    }
    if (lane == 0) {
#pragma unroll
        for (int t = 0; t < NBINS; ++t) {
            s_c[wave][t] = conf[t]; s_n[wave][t] = cntd[t]; s_r[wave][t] = cord[t];
        }
    }
    __syncthreads();

    if (tid == 0) {
        double S[NBINS + 1], G[NBINS + 1], R[NBINS];
        for (int t = 0; t < NBINS; ++t) {
            G[t] = s_n[0][t] + s_n[1][t] + s_n[2][t] + s_n[3][t];
            R[t] = s_r[0][t] + s_r[1][t] + s_r[2][t] + s_r[3][t];
            S[t] = s_c[0][t] + s_c[1][t] + s_c[2][t] + s_c[3][t];
        }
        S[NBINS] = 0.0; G[NBINS] = 0.0;

        double total = 0.0, ece = 0.0;
        for (int j = 0; j < NBINS; ++j) {
            const double c  = G[j] - G[j + 1];     // per-bin count
            const double sc = S[j] - S[j + 1];     // per-bin conf sum
            const double ba = R[j] / c;
            total += c;
            ece   += fabs(sc / c - ba) * c;
            out[1 + j]  = (float)((float)((j + 1) * 0.1) - 0.05f);  // centers
            out[11 + j] = (float)ba;
        }
        out[0] = (float)(ece / total);
    }
}

extern "C" void kernel_launch(void* const* d_in, const int* in_sizes, int n_in,
                              void* d_out, int out_size, void* d_ws, size_t ws_size,
                              hipStream_t stream)
{
    const float* probs  = (const float*)d_in[0];
    const int*   labels = (const int*)  d_in[1];
    float*       out    = (float*)d_out;
    const int n      = in_sizes[1];       // N_SAMPLES
    const int npairs = n / 2;

    float* part = (float*)d_ws;           // fully rewritten each call — no memset

    ece_pass<<<GRID, BLOCK, 0, stream>>>((const float4*)probs, (const int2*)labels,
                                         part, npairs);
    ece_reduce<<<1, 256, 0, stream>>>(part, out);
}

// Round 10
// 40.602 us; speedup vs baseline: 1.1218x; 1.1218x over previous
//
#include <hip/hip_runtime.h>

#define NBINS 10
#define C 10

constexpr int BLOCK = 256;
constexpr int GRID  = 2048;
constexpr int PSTR  = 32;     // padded partial-row stride (floats)

// d_ws float layout: 3 segments of GRID*PSTR floats (conf | cnt | cor).
// Every slot read by ece_reduce is rewritten every call — no memset needed.

__global__ __launch_bounds__(BLOCK) void ece_pass(
    const float4* __restrict__ p4,
    const int2*   __restrict__ l2,
    float*        __restrict__ part,
    int npairs)
{
    __shared__ float        s_red[8 * NBINS];
    __shared__ unsigned int s_cor[NBINS];

    const int tid  = threadIdx.x;
    const int lane = tid & 63, wave = tid >> 6;

    const float EDGE[NBINS] = {
        (float)(0*0.1), (float)(1*0.1), (float)(2*0.1), (float)(3*0.1), (float)(4*0.1),
        (float)(5*0.1), (float)(6*0.1), (float)(7*0.1), (float)(8*0.1), (float)(9*0.1)};

    if (tid < NBINS) s_cor[tid] = 0u;
    __syncthreads();

    float        conf[NBINS];
    unsigned int cnt1[NBINS];           // edges 1..9 ([0] unused)
    unsigned int np = 0;                // pairs processed -> cnt[0] = 20*np (x>0 always)
#pragma unroll
    for (int t = 0; t < NBINS; ++t) { conf[t] = 0.0f; cnt1[t] = 0u; }

    // Edges 0.1..0.4: every element can land here -> full ladder.
#define LADDER_LOW(x)                                                       \
        {                                                                   \
            _Pragma("unroll")                                               \
            for (int t_ = 1; t_ <= 4; ++t_) {                               \
                const bool g_ = (x) > EDGE[t_];                             \
                cnt1[t_] += g_ ? 1u : 0u;                                   \
                conf[t_] += g_ ? (x) : 0.0f;                                \
            }                                                               \
        }
    // Edges 0.5..0.9: sum(probs)==1 -> at most one element > 0.5, and it is
    // the sample max. Ladder only the max value (mA / mB).
#define LADDER_HIGH(x)                                                      \
        {                                                                   \
            _Pragma("unroll")                                               \
            for (int t_ = 5; t_ < NBINS; ++t_) {                            \
                const bool g_ = (x) > EDGE[t_];                             \
                cnt1[t_] += g_ ? 1u : 0u;                                   \
                conf[t_] += g_ ? (x) : 0.0f;                                \
            }                                                               \
        }

    for (int pr = blockIdx.x * BLOCK + tid; pr < npairs; pr += GRID * BLOCK) {
        const float4* rw = p4 + (size_t)pr * 5;    // 80 B contiguous per lane
        const float4 q0 = rw[0], q1 = rw[1], q2 = rw[2], q3 = rw[3], q4 = rw[4];
        const int2 lab = l2[pr];
        ++np;

        // ---- conf[0]: plain sum of all 20 (cnt[0] is analytic) ----
        conf[0] += (((q0.x + q0.y) + (q0.z + q0.w)) + ((q1.x + q1.y) + (q1.z + q1.w)))
                 + (((q2.x + q2.y) + (q2.z + q2.w)) + ((q3.x + q3.y) + (q3.z + q3.w)))
                 + ((q4.x + q4.y) + (q4.z + q4.w));

        // ---- low ladder over all 20 elements ----
        LADDER_LOW(q0.x); LADDER_LOW(q0.y); LADDER_LOW(q0.z); LADDER_LOW(q0.w);
        LADDER_LOW(q1.x); LADDER_LOW(q1.y); LADDER_LOW(q1.z); LADDER_LOW(q1.w);
        LADDER_LOW(q2.x); LADDER_LOW(q2.y); LADDER_LOW(q2.z); LADDER_LOW(q2.w);
        LADDER_LOW(q3.x); LADDER_LOW(q3.y); LADDER_LOW(q3.z); LADDER_LOW(q3.w);
        LADDER_LOW(q4.x); LADDER_LOW(q4.y); LADDER_LOW(q4.z); LADDER_LOW(q4.w);

        // ---- sample maxes (needed for high ladder AND correctness check) ----
        const float mA = fmaxf(fmaxf(fmaxf(fmaxf(q0.x, q0.y), fmaxf(q0.z, q0.w)),
                                     fmaxf(fmaxf(q1.x, q1.y), fmaxf(q1.z, q1.w))),
                               fmaxf(q2.x, q2.y));
        const float mB = fmaxf(fmaxf(fmaxf(fmaxf(q2.z, q2.w), fmaxf(q3.x, q3.y)),
                                     fmaxf(fmaxf(q3.z, q3.w), fmaxf(q4.x, q4.y))),
                               fmaxf(q4.z, q4.w));

        // ---- high ladder: only the maxes can exceed 0.5 ----
        LADDER_HIGH(mA);
        LADDER_HIGH(mB);

        // ---- correct checks: p[label] == max ----
        float plA = q0.x;                          // p[label] via cndmask chain
        plA = (lab.x == 1) ? q0.y : plA;
        plA = (lab.x == 2) ? q0.z : plA;
        plA = (lab.x == 3) ? q0.w : plA;
        plA = (lab.x == 4) ? q1.x : plA;
        plA = (lab.x == 5) ? q1.y : plA;
        plA = (lab.x == 6) ? q1.z : plA;
        plA = (lab.x == 7) ? q1.w : plA;
        plA = (lab.x == 8) ? q2.x : plA;
        plA = (lab.x == 9) ? q2.y : plA;
        if (plA >= mA) {                           // max >= 0.1 -> bin idx always >= 0
            const int im = min((int)ceilf(plA * 10.0f) - 1, NBINS - 1);
            atomicAdd(&s_cor[im], 1u);             // LDS only, ~10% hit rate
        }

        float plB = q2.z;
        plB = (lab.y == 1) ? q2.w : plB;
        plB = (lab.y == 2) ? q3.x : plB;
        plB = (lab.y == 3) ? q3.y : plB;
        plB = (lab.y == 4) ? q3.z : plB;
        plB = (lab.y == 5) ? q3.w : plB;
        plB = (lab.y == 6) ? q4.x : plB;
        plB = (lab.y == 7) ? q4.y : plB;
        plB = (lab.y == 8) ? q4.z : plB;
        plB = (lab.y == 9) ? q4.w : plB;
        if (plB >= mB) {
            const int im = min((int)ceilf(plB * 10.0f) - 1, NBINS - 1);
            atomicAdd(&s_cor[im], 1u);
        }
    }
#undef LADDER_LOW
#undef LADDER_HIGH

    unsigned int cnt0 = 20u * np;       // all elements > 0 (softmax output)

    // ---- 64-lane butterfly ----
#pragma unroll
    for (int t = 0; t < NBINS; ++t)
        for (int o = 32; o > 0; o >>= 1)
            conf[t] += __shfl_xor(conf[t], o, 64);
    for (int o = 32; o > 0; o >>= 1) cnt0 += __shfl_xor(cnt0, o, 64);
#pragma unroll
    for (int t = 1; t < NBINS; ++t)
        for (int o = 32; o > 0; o >>= 1)
            cnt1[t] += __shfl_xor(cnt1[t], o, 64);

    if (lane == 0) {
#pragma unroll
        for (int t = 0; t < NBINS; ++t) {
            s_red[wave * NBINS + t]       = conf[t];
            s_red[(4 + wave) * NBINS + t] = (t == 0) ? (float)cnt0 : (float)cnt1[t];
        }
    }
    __syncthreads();

    if (tid < 12) {   // 12 slots (2 zero pads) so reduce can float4-load
        float fc = 0.0f, fn = 0.0f;
        if (tid < NBINS) {
#pragma unroll
            for (int w = 0; w < 4; ++w) {
                fc += s_red[w * NBINS + tid];
                fn += s_red[(4 + w) * NBINS + tid];
            }
        }
        const float fr = (tid < NBINS) ? (float)s_cor[tid] : 0.0f;
        part[(size_t)blockIdx.x * PSTR + tid]                    = fc;
        part[(size_t)GRID * PSTR + blockIdx.x * PSTR + tid]      = fn;
        part[(size_t)2 * GRID * PSTR + blockIdx.x * PSTR + tid]  = fr;
    }
}

__global__ __launch_bounds__(256) void ece_reduce(
    const float* __restrict__ part,
    float* __restrict__ out)
{
    __shared__ double s_c[4][NBINS];
    __shared__ double s_n[4][NBINS];
    __shared__ double s_r[4][NBINS];

    const int tid = threadIdx.x;
    const int lane = tid & 63, wave = tid >> 6;

    double conf[NBINS], cntd[NBINS], cord[NBINS];
#pragma unroll
    for (int t = 0; t < NBINS; ++t) { conf[t] = 0.0; cntd[t] = 0.0; cord[t] = 0.0; }

    for (int b = tid; b < GRID; b += 256) {
        const float4* rc = reinterpret_cast<const float4*>(part + (size_t)b * PSTR);
        const float4* rn = reinterpret_cast<const float4*>(part + (size_t)GRID * PSTR + b * PSTR);
        const float4* rr = reinterpret_cast<const float4*>(part + (size_t)2 * GRID * PSTR + b * PSTR);
        const float4 c0 = rc[0], c1 = rc[1], c2 = rc[2];
        const float4 n0 = rn[0], n1 = rn[1], n2 = rn[2];
        const float4 r0 = rr[0], r1 = rr[1], r2 = rr[2];
        const float cf[12] = {c0.x,c0.y,c0.z,c0.w, c1.x,c1.y,c1.z,c1.w, c2.x,c2.y,c2.z,c2.w};
        const float nf[12] = {n0.x,n0.y,n0.z,n0.w, n1.x,n1.y,n1.z,n1.w, n2.x,n2.y,n2.z,n2.w};
        const float rf[12] = {r0.x,r0.y,r0.z,r0.w, r1.x,r1.y,r1.z,r1.w, r2.x,r2.y,r2.z,r2.w};
#pragma unroll
        for (int t = 0; t < NBINS; ++t) {
            conf[t] += (double)cf[t];
            cntd[t] += (double)nf[t];
            cord[t] += (double)rf[t];
        }
    }

#pragma unroll
    for (int t = 0; t < NBINS; ++t) {
        for (int o = 32; o > 0; o >>= 1) {
            conf[t] += __shfl_xor(conf[t], o, 64);
            cntd[t] += __shfl_xor(cntd[t], o, 64);
            cord[t] += __shfl_xor(cord[t], o, 64);
        }
    }
    if (lane == 0) {
#pragma unroll
        for (int t = 0; t < NBINS; ++t) {
            s_c[wave][t] = conf[t]; s_n[wave][t] = cntd[t]; s_r[wave][t] = cord[t];
        }
    }
    __syncthreads();

    if (tid == 0) {
        double S[NBINS + 1], G[NBINS + 1], R[NBINS];
        for (int t = 0; t < NBINS; ++t) {
            G[t] = s_n[0][t] + s_n[1][t] + s_n[2][t] + s_n[3][t];
            R[t] = s_r[0][t] + s_r[1][t] + s_r[2][t] + s_r[3][t];
            S[t] = s_c[0][t] + s_c[1][t] + s_c[2][t] + s_c[3][t];
        }
        S[NBINS] = 0.0; G[NBINS] = 0.0;

        double total = 0.0, ece = 0.0;
        for (int j = 0; j < NBINS; ++j) {
            const double c  = G[j] - G[j + 1];     // per-bin count
            const double sc = S[j] - S[j + 1];     // per-bin conf sum
            const double ba = R[j] / c;
            total += c;
            ece   += fabs(sc / c - ba) * c;
            out[1 + j]  = (float)((float)((j + 1) * 0.1) - 0.05f);  // centers
            out[11 + j] = (float)ba;
        }
        out[0] = (float)(ece / total);
    }
}

extern "C" void kernel_launch(void* const* d_in, const int* in_sizes, int n_in,
                              void* d_out, int out_size, void* d_ws, size_t ws_size,
                              hipStream_t stream)
{
    const float* probs  = (const float*)d_in[0];
    const int*   labels = (const int*)  d_in[1];
    float*       out    = (float*)d_out;
    const int n      = in_sizes[1];       // N_SAMPLES
    const int npairs = n / 2;

    float* part = (float*)d_ws;           // fully rewritten each call — no memset

    ece_pass<<<GRID, BLOCK, 0, stream>>>((const float4*)probs, (const int2*)labels,
                                         part, npairs);
    ece_reduce<<<1, 256, 0, stream>>>(part, out);
}

// Round 11
// 37.652 us; speedup vs baseline: 1.2097x; 1.0784x over previous
//
#include <hip/hip_runtime.h>

#define NBINS 10
#define C 10

constexpr int BLOCK = 256;
constexpr int GRID  = 1024;
constexpr int PSTR  = 32;     // padded partial-row stride (floats)

// d_ws float layout: 3 segments of GRID*PSTR floats (conf | cnt | cor).
// Every slot read by ece_reduce is rewritten every call — no memset needed.

__global__ __launch_bounds__(BLOCK) void ece_pass(
    const float4* __restrict__ p4,
    const int2*   __restrict__ l2,
    float*        __restrict__ part,
    int npairs)
{
    __shared__ float        s_red[8 * NBINS];
    __shared__ unsigned int s_cor[NBINS];

    const int tid  = threadIdx.x;
    const int lane = tid & 63, wave = tid >> 6;

    const float EDGE[NBINS] = {
        (float)(0*0.1), (float)(1*0.1), (float)(2*0.1), (float)(3*0.1), (float)(4*0.1),
        (float)(5*0.1), (float)(6*0.1), (float)(7*0.1), (float)(8*0.1), (float)(9*0.1)};

    if (tid < NBINS) s_cor[tid] = 0u;
    __syncthreads();

    float        conf[NBINS];
    unsigned int cnt1[NBINS];           // edges 1..9 ([0] unused)
    unsigned int np = 0;                // pairs processed -> cnt[0] = 20*np (x>0 always)
#pragma unroll
    for (int t = 0; t < NBINS; ++t) { conf[t] = 0.0f; cnt1[t] = 0u; }

    // Edges 0.1..0.4: every element can land here -> full ladder.
#define LADDER_LOW(x)                                                       \
        {                                                                   \
            _Pragma("unroll")                                               \
            for (int t_ = 1; t_ <= 4; ++t_) {                               \
                const bool g_ = (x) > EDGE[t_];                             \
                cnt1[t_] += g_ ? 1u : 0u;                                   \
                conf[t_] += g_ ? (x) : 0.0f;                                \
            }                                                               \
        }
    // Edges 0.5..0.9: sum(probs)==1 -> at most one element > 0.5, and it is
    // the sample max. Ladder only the max value (mA / mB).
#define LADDER_HIGH(x)                                                      \
        {                                                                   \
            _Pragma("unroll")                                               \
            for (int t_ = 5; t_ < NBINS; ++t_) {                            \
                const bool g_ = (x) > EDGE[t_];                             \
                cnt1[t_] += g_ ? 1u : 0u;                                   \
                conf[t_] += g_ ? (x) : 0.0f;                                \
            }                                                               \
        }

    // ---- software-pipelined main loop: prefetch next pair while processing cur ----
    const int stride = GRID * BLOCK;
    int pr = blockIdx.x * BLOCK + tid;

    float4 c0, c1, c2, c3, c4; int2 clab;
    if (pr < npairs) {                          // prologue load
        const float4* rw = p4 + (size_t)pr * 5;
        c0 = rw[0]; c1 = rw[1]; c2 = rw[2]; c3 = rw[3]; c4 = rw[4];
        clab = l2[pr];
    }

    while (pr < npairs) {
        const int nx = pr + stride;
        float4 n0, n1, n2, n3, n4; int2 nlab;
        if (nx < npairs) {                      // issue next loads BEFORE compute
            const float4* rw = p4 + (size_t)nx * 5;
            n0 = rw[0]; n1 = rw[1]; n2 = rw[2]; n3 = rw[3]; n4 = rw[4];
            nlab = l2[nx];
        }

        ++np;

        // ---- conf[0]: plain sum of all 20 (cnt[0] is analytic) ----
        conf[0] += (((c0.x + c0.y) + (c0.z + c0.w)) + ((c1.x + c1.y) + (c1.z + c1.w)))
                 + (((c2.x + c2.y) + (c2.z + c2.w)) + ((c3.x + c3.y) + (c3.z + c3.w)))
                 + ((c4.x + c4.y) + (c4.z + c4.w));

        // ---- low ladder over all 20 elements ----
        LADDER_LOW(c0.x); LADDER_LOW(c0.y); LADDER_LOW(c0.z); LADDER_LOW(c0.w);
        LADDER_LOW(c1.x); LADDER_LOW(c1.y); LADDER_LOW(c1.z); LADDER_LOW(c1.w);
        LADDER_LOW(c2.x); LADDER_LOW(c2.y); LADDER_LOW(c2.z); LADDER_LOW(c2.w);
        LADDER_LOW(c3.x); LADDER_LOW(c3.y); LADDER_LOW(c3.z); LADDER_LOW(c3.w);
        LADDER_LOW(c4.x); LADDER_LOW(c4.y); LADDER_LOW(c4.z); LADDER_LOW(c4.w);

        // ---- sample maxes (high ladder + correctness check) ----
        const float mA = fmaxf(fmaxf(fmaxf(fmaxf(c0.x, c0.y), fmaxf(c0.z, c0.w)),
                                     fmaxf(fmaxf(c1.x, c1.y), fmaxf(c1.z, c1.w))),
                               fmaxf(c2.x, c2.y));
        const float mB = fmaxf(fmaxf(fmaxf(fmaxf(c2.z, c2.w), fmaxf(c3.x, c3.y)),
                                     fmaxf(fmaxf(c3.z, c3.w), fmaxf(c4.x, c4.y))),
                               fmaxf(c4.z, c4.w));

        LADDER_HIGH(mA);
        LADDER_HIGH(mB);

        // ---- correct checks: p[label] == max ----
        float plA = c0.x;                       // p[label] via cndmask chain
        plA = (clab.x == 1) ? c0.y : plA;
        plA = (clab.x == 2) ? c0.z : plA;
        plA = (clab.x == 3) ? c0.w : plA;
        plA = (clab.x == 4) ? c1.x : plA;
        plA = (clab.x == 5) ? c1.y : plA;
        plA = (clab.x == 6) ? c1.z : plA;
        plA = (clab.x == 7) ? c1.w : plA;
        plA = (clab.x == 8) ? c2.x : plA;
        plA = (clab.x == 9) ? c2.y : plA;
        if (plA >= mA) {                        // max >= 0.1 -> bin idx always >= 0
            const int im = min((int)ceilf(plA * 10.0f) - 1, NBINS - 1);
            atomicAdd(&s_cor[im], 1u);          // LDS only, ~10% hit rate
        }

        float plB = c2.z;
        plB = (clab.y == 1) ? c2.w : plB;
        plB = (clab.y == 2) ? c3.x : plB;
        plB = (clab.y == 3) ? c3.y : plB;
        plB = (clab.y == 4) ? c3.z : plB;
        plB = (clab.y == 5) ? c3.w : plB;
        plB = (clab.y == 6) ? c4.x : plB;
        plB = (clab.y == 7) ? c4.y : plB;
        plB = (clab.y == 8) ? c4.z : plB;
        plB = (clab.y == 9) ? c4.w : plB;
        if (plB >= mB) {
            const int im = min((int)ceilf(plB * 10.0f) - 1, NBINS - 1);
            atomicAdd(&s_cor[im], 1u);
        }

        // ---- rotate pipeline ----
        pr = nx;
        c0 = n0; c1 = n1; c2 = n2; c3 = n3; c4 = n4; clab = nlab;
    }
#undef LADDER_LOW
#undef LADDER_HIGH

    unsigned int cnt0 = 20u * np;       // all elements > 0 (softmax output)

    // ---- 64-lane butterfly ----
#pragma unroll
    for (int t = 0; t < NBINS; ++t)
        for (int o = 32; o > 0; o >>= 1)
            conf[t] += __shfl_xor(conf[t], o, 64);
    for (int o = 32; o > 0; o >>= 1) cnt0 += __shfl_xor(cnt0, o, 64);
#pragma unroll
    for (int t = 1; t < NBINS; ++t)
        for (int o = 32; o > 0; o >>= 1)
            cnt1[t] += __shfl_xor(cnt1[t], o, 64);

    if (lane == 0) {
#pragma unroll
        for (int t = 0; t < NBINS; ++t) {
            s_red[wave * NBINS + t]       = conf[t];
            s_red[(4 + wave) * NBINS + t] = (t == 0) ? (float)cnt0 : (float)cnt1[t];
        }
    }
    __syncthreads();

    if (tid < 12) {   // 12 slots (2 zero pads) so reduce can float4-load
        float fc = 0.0f, fn = 0.0f;
        if (tid < NBINS) {
#pragma unroll
            for (int w = 0; w < 4; ++w) {
                fc += s_red[w * NBINS + tid];
                fn += s_red[(4 + w) * NBINS + tid];
            }
        }
        const float fr = (tid < NBINS) ? (float)s_cor[tid] : 0.0f;
        part[(size_t)blockIdx.x * PSTR + tid]                    = fc;
        part[(size_t)GRID * PSTR + blockIdx.x * PSTR + tid]      = fn;
        part[(size_t)2 * GRID * PSTR + blockIdx.x * PSTR + tid]  = fr;
    }
}

__global__ __launch_bounds__(256) void ece_reduce(
    const float* __restrict__ part,
    float* __restrict__ out)
{
    __shared__ double s_c[4][NBINS];
    __shared__ double s_n[4][NBINS];
    __shared__ double s_r[4][NBINS];

    const int tid = threadIdx.x;
    const int lane = tid & 63, wave = tid >> 6;

    double conf[NBINS], cntd[NBINS], cord[NBINS];
#pragma unroll
    for (int t = 0; t < NBINS; ++t) { conf[t] = 0.0; cntd[t] = 0.0; cord[t] = 0.0; }

    for (int b = tid; b < GRID; b += 256) {
        const float4* rc = reinterpret_cast<const float4*>(part + (size_t)b * PSTR);
        const float4* rn = reinterpret_cast<const float4*>(part + (size_t)GRID * PSTR + b * PSTR);
        const float4* rr = reinterpret_cast<const float4*>(part + (size_t)2 * GRID * PSTR + b * PSTR);
        const float4 c0 = rc[0], c1 = rc[1], c2 = rc[2];
        const float4 n0 = rn[0], n1 = rn[1], n2 = rn[2];
        const float4 r0 = rr[0], r1 = rr[1], r2 = rr[2];
        const float cf[12] = {c0.x,c0.y,c0.z,c0.w, c1.x,c1.y,c1.z,c1.w, c2.x,c2.y,c2.z,c2.w};
        const float nf[12] = {n0.x,n0.y,n0.z,n0.w, n1.x,n1.y,n1.z,n1.w, n2.x,n2.y,n2.z,n2.w};
        const float rf[12] = {r0.x,r0.y,r0.z,r0.w, r1.x,r1.y,r1.z,r1.w, r2.x,r2.y,r2.z,r2.w};
#pragma unroll
        for (int t = 0; t < NBINS; ++t) {
            conf[t] += (double)cf[t];
            cntd[t] += (double)nf[t];
            cord[t] += (double)rf[t];
        }
    }

#pragma unroll
    for (int t = 0; t < NBINS; ++t) {
        for (int o = 32; o > 0; o >>= 1) {
            conf[t] += __shfl_xor(conf[t], o, 64);
            cntd[t] += __shfl_xor(cntd[t], o, 64);
            cord[t] += __shfl_xor(cord[t], o, 64);
        }
    }
    if (lane == 0) {
#pragma unroll
        for (int t = 0; t < NBINS; ++t) {
            s_c[wave][t] = conf[t]; s_n[wave][t] = cntd[t]; s_r[wave][t] = cord[t];
        }
    }
    __syncthreads();

    if (tid == 0) {
        double S[NBINS + 1], G[NBINS + 1], R[NBINS];
        for (int t = 0; t < NBINS; ++t) {
            G[t] = s_n[0][t] + s_n[1][t] + s_n[2][t] + s_n[3][t];
            R[t] = s_r[0][t] + s_r[1][t] + s_r[2][t] + s_r[3][t];
            S[t] = s_c[0][t] + s_c[1][t] + s_c[2][t] + s_c[3][t];
        }
        S[NBINS] = 0.0; G[NBINS] = 0.0;

        double total = 0.0, ece = 0.0;
        for (int j = 0; j < NBINS; ++j) {
            const double c  = G[j] - G[j + 1];     // per-bin count
            const double sc = S[j] - S[j + 1];     // per-bin conf sum
            const double ba = R[j] / c;
            total += c;
            ece   += fabs(sc / c - ba) * c;
            out[1 + j]  = (float)((float)((j + 1) * 0.1) - 0.05f);  // centers
            out[11 + j] = (float)ba;
        }
        out[0] = (float)(ece / total);
    }
}

extern "C" void kernel_launch(void* const* d_in, const int* in_sizes, int n_in,
                              void* d_out, int out_size, void* d_ws, size_t ws_size,
                              hipStream_t stream)
{
    const float* probs  = (const float*)d_in[0];
    const int*   labels = (const int*)  d_in[1];
    float*       out    = (float*)d_out;
    const int n      = in_sizes[1];       // N_SAMPLES
    const int npairs = n / 2;

    float* part = (float*)d_ws;           // fully rewritten each call — no memset

    ece_pass<<<GRID, BLOCK, 0, stream>>>((const float4*)probs, (const int2*)labels,
                                         part, npairs);
    ece_reduce<<<1, 256, 0, stream>>>(part, out);
}